// Round 2
// baseline (352.145 us; speedup 1.0000x reference)
//
#include <hip/hip_runtime.h>

// Fused GQA attention block for MI355X (gfx950).
// Pipeline: cvt(fp32->bf16) -> QKV GEMM(+bias, V stored transposed) -> RoPE ->
//           flash attention (causal, GQA, sink renorm) -> O-proj GEMM(+bias, fp32 out).
// All matmul in bf16 MFMA 16x16x32, fp32 accum (threshold is bf16-level).

#define S_LEN 2048
#define DIM_  2048
#define QK_LD 2560   // q cols 2048 + k cols 512 in the qk buffer

typedef __attribute__((ext_vector_type(8))) __bf16 bf16x8;
typedef __attribute__((ext_vector_type(4))) float f32x4;
typedef __attribute__((ext_vector_type(4))) unsigned short us4;

__device__ __forceinline__ unsigned short f2bf(float f) {
    union { float f; unsigned u; } v; v.f = f;
    unsigned r = v.u + 0x7FFFu + ((v.u >> 16) & 1u);   // RNE
    return (unsigned short)(r >> 16);
}
__device__ __forceinline__ float bf2f(unsigned short u) {
    union { unsigned u; float f; } v; v.u = ((unsigned)u) << 16;
    return v.f;
}

// XOR swizzles: 16B-chunk permutation within a row so column-slice ds_read_b128
// across consecutive rows spreads over banks (2-way residue = free per m136).
// [r][32] bf16 tiles (64B rows, 4 chunks):
__device__ __forceinline__ int swz32(int r, int ch) { return r*32 + ((ch ^ ((r >> 1) & 3)) << 3); }
// [r][64] bf16 tiles (128B rows, 8 chunks):
__device__ __forceinline__ int swz64(int r, int ch) { return r*64 + ((ch ^ (r & 7)) << 3); }

__global__ void cvt_f32_bf16(const float* __restrict__ src, unsigned short* __restrict__ dst, int n) {
    const int i = (blockIdx.x * 256 + threadIdx.x) * 4;
    if (i + 4 <= n) {
        const float4 v = *reinterpret_cast<const float4*>(src + i);
        us4 o = { f2bf(v.x), f2bf(v.y), f2bf(v.z), f2bf(v.w) };
        *reinterpret_cast<us4*>(dst + i) = o;
    }
}

__global__ void build_bias(const float* __restrict__ qb, const float* __restrict__ kb,
                           const float* __restrict__ vb, float* __restrict__ out) {
    const int i = blockIdx.x * 256 + threadIdx.x;   // 3072 total
    if (i < 2048) out[i] = qb[i];
    else if (i < 2560) out[i] = kb[i - 2048];
    else if (i < 3072) out[i] = vb[i - 2560];
}

// C[m,n] = sum_k A[m,k]*B[n,k] + bias[n]   (B^T-input GEMM, m97-style 128^2 tile)
// MODE 0: QKV epilogue -> Cqk bf16 [2048][2560] for n<2560, V transposed into Vt[n-2560][s]
// MODE 1: fp32 out (ldc 2048) -> Cf
template<int MODE>
__global__ __launch_bounds__(256)
void gemm_bt(const unsigned short* __restrict__ A,
             const unsigned short* __restrict__ B,
             const float* __restrict__ bias,
             unsigned short* __restrict__ Cqk,
             unsigned short* __restrict__ Vt,
             float* __restrict__ Cf,
             int K)
{
    __shared__ unsigned short As[128 * 32];
    __shared__ unsigned short Bs[128 * 32];
    const int t = threadIdx.x;
    const int lane = t & 63;
    const int w = t >> 6;
    const int wr = w >> 1, wc = w & 1;
    const int lq = lane & 15;
    const int g = lane >> 4;
    const int m0 = blockIdx.y * 128;
    const int n0 = blockIdx.x * 128;

    const f32x4 z = {0.f, 0.f, 0.f, 0.f};
    f32x4 acc[4][4];
    #pragma unroll
    for (int i = 0; i < 4; i++)
        #pragma unroll
        for (int j = 0; j < 4; j++) acc[i][j] = z;

    for (int k0 = 0; k0 < K; k0 += 32) {
        #pragma unroll
        for (int i = 0; i < 2; i++) {
            const int eo = (i * 256 + t) * 8;
            const int r = eo >> 5;
            const int ch = (eo >> 3) & 3;
            *reinterpret_cast<bf16x8*>(&As[swz32(r, ch)]) =
                *reinterpret_cast<const bf16x8*>(&A[(size_t)(m0 + r) * K + k0 + (ch << 3)]);
            *reinterpret_cast<bf16x8*>(&Bs[swz32(r, ch)]) =
                *reinterpret_cast<const bf16x8*>(&B[(size_t)(n0 + r) * K + k0 + (ch << 3)]);
        }
        __syncthreads();
        bf16x8 a[4], b[4];
        #pragma unroll
        for (int mi = 0; mi < 4; mi++)
            a[mi] = *reinterpret_cast<const bf16x8*>(&As[swz32(wr * 64 + mi * 16 + lq, g)]);
        #pragma unroll
        for (int ni = 0; ni < 4; ni++)
            b[ni] = *reinterpret_cast<const bf16x8*>(&Bs[swz32(wc * 64 + ni * 16 + lq, g)]);
        #pragma unroll
        for (int mi = 0; mi < 4; mi++)
            #pragma unroll
            for (int ni = 0; ni < 4; ni++)
                acc[mi][ni] = __builtin_amdgcn_mfma_f32_16x16x32_bf16(a[mi], b[ni], acc[mi][ni], 0, 0, 0);
        __syncthreads();
    }

    // epilogue: C/D layout col = lane&15, row = (lane>>4)*4 + reg  [verified m89/m91]
    #pragma unroll
    for (int mi = 0; mi < 4; mi++) {
        const int row0 = m0 + wr * 64 + mi * 16 + g * 4;
        #pragma unroll
        for (int ni = 0; ni < 4; ni++) {
            const int col = n0 + wc * 64 + ni * 16 + lq;
            const float bv = bias[col];
            if (MODE == 1) {
                #pragma unroll
                for (int j = 0; j < 4; j++)
                    Cf[(size_t)(row0 + j) * 2048 + col] = acc[mi][ni][j] + bv;
            } else {
                if (col < 2560) {
                    #pragma unroll
                    for (int j = 0; j < 4; j++)
                        Cqk[(size_t)(row0 + j) * QK_LD + col] = f2bf(acc[mi][ni][j] + bv);
                } else {
                    us4 pk;
                    #pragma unroll
                    for (int j = 0; j < 4; j++) pk[j] = f2bf(acc[mi][ni][j] + bv);
                    *reinterpret_cast<us4*>(&Vt[(size_t)(col - 2560) * S_LEN + row0]) = pk;
                }
            }
        }
    }
}

// In-place RoPE on q (heads 0..31) and k (heads 32..39 => cols 2048..2559) of qk buffer.
__global__ void rope_kernel(unsigned short* __restrict__ qk, const float* __restrict__ rope) {
    const int idx = blockIdx.x * 256 + threadIdx.x;      // 2048*40*32 exact
    const int s = idx / 1280;
    const int rem = idx - s * 1280;
    const int head = rem >> 5;
    const int p = rem & 31;
    const size_t base = (size_t)s * QK_LD + head * 64 + p;
    const float c = rope[s * 128 + p];           // cos duplicated across halves
    const float sn = rope[s * 128 + 64 + p];     // sin duplicated across halves
    const float x0 = bf2f(qk[base]);
    const float x1 = bf2f(qk[base + 32]);
    qk[base]      = f2bf(x0 * c - x1 * sn);
    qk[base + 32] = f2bf(x1 * c + x0 * sn);
}

// Flash attention: block = (q-tile of 64 rows, head). 4 waves x 16 q-rows each.
__global__ __launch_bounds__(256)
void attn_kernel(const unsigned short* __restrict__ qk,
                 const unsigned short* __restrict__ vt,
                 const float* __restrict__ sinks,
                 unsigned short* __restrict__ aout)
{
    const int qb = blockIdx.x;
    const int h = blockIdx.y;
    const int hkv = h >> 2;                      // repeat_interleave: kv head = h/4
    const int t = threadIdx.x;
    const int lane = t & 63;
    const int w = t >> 6;
    const int lq = lane & 15;
    const int g = lane >> 4;

    __shared__ unsigned short Ks[64 * 64];       // [kv][d], swizzled
    __shared__ unsigned short Vs[64 * 64];       // [d][kv] (V^T), swizzled
    __shared__ unsigned short Ps[4][16 * 64];    // per-wave P [q][kv], swizzled

    const int qrow_a = qb * 64 + w * 16 + lq;    // A-frag row (QK^T)
    const int qrow_c = qb * 64 + w * 16 + g * 4; // C-layout row base

    bf16x8 aq[2];
    #pragma unroll
    for (int c = 0; c < 2; c++)
        aq[c] = *reinterpret_cast<const bf16x8*>(&qk[(size_t)qrow_a * QK_LD + h * 64 + c * 32 + g * 8]);

    const f32x4 z = {0.f, 0.f, 0.f, 0.f};
    f32x4 acc_o[4];
    #pragma unroll
    for (int df = 0; df < 4; df++) acc_o[df] = z;
    float mrow[4] = {-1e30f, -1e30f, -1e30f, -1e30f};
    float lrow[4] = {0.f, 0.f, 0.f, 0.f};

    unsigned short* Pw = &Ps[w][0];

    for (int tkv = 0; tkv <= qb; tkv++) {
        const int kv0 = tkv * 64;
        #pragma unroll
        for (int i = 0; i < 2; i++) {
            const int eo = (i * 256 + t) * 8;
            const int r = eo >> 6;
            const int ch = (eo >> 3) & 7;
            *reinterpret_cast<bf16x8*>(&Ks[swz64(r, ch)]) =
                *reinterpret_cast<const bf16x8*>(&qk[(size_t)(kv0 + r) * QK_LD + 2048 + hkv * 64 + (ch << 3)]);
            *reinterpret_cast<bf16x8*>(&Vs[swz64(r, ch)]) =
                *reinterpret_cast<const bf16x8*>(&vt[(size_t)(hkv * 64 + r) * S_LEN + kv0 + (ch << 3)]);
        }
        __syncthreads();

        // S = Q K^T  (16 q-rows x 64 kv)
        f32x4 sc[4];
        #pragma unroll
        for (int kf = 0; kf < 4; kf++) {
            sc[kf] = z;
            #pragma unroll
            for (int c = 0; c < 2; c++) {
                const bf16x8 bk = *reinterpret_cast<const bf16x8*>(&Ks[swz64(kf * 16 + lq, c * 4 + g)]);
                sc[kf] = __builtin_amdgcn_mfma_f32_16x16x32_bf16(aq[c], bk, sc[kf], 0, 0, 0);
            }
        }

        // scale + causal mask
        const bool diag = (tkv == qb);
        #pragma unroll
        for (int kf = 0; kf < 4; kf++) {
            const int kvcol = kv0 + kf * 16 + lq;
            #pragma unroll
            for (int j = 0; j < 4; j++) {
                float v = sc[kf][j] * 0.125f;
                if (diag && (kvcol > qrow_c + j)) v = -1e30f;
                sc[kf][j] = v;
            }
        }

        // online softmax per q-row: reduce across the 16-lane group
        #pragma unroll
        for (int j = 0; j < 4; j++) {
            float mx = fmaxf(fmaxf(sc[0][j], sc[1][j]), fmaxf(sc[2][j], sc[3][j]));
            mx = fmaxf(mx, __shfl_xor(mx, 1));
            mx = fmaxf(mx, __shfl_xor(mx, 2));
            mx = fmaxf(mx, __shfl_xor(mx, 4));
            mx = fmaxf(mx, __shfl_xor(mx, 8));
            const float mnew = fmaxf(mrow[j], mx);
            const float resc = __expf(mrow[j] - mnew);   // 0 on first tile (underflow)
            mrow[j] = mnew;
            float sum = 0.f;
            #pragma unroll
            for (int kf = 0; kf < 4; kf++) {
                const float p = __expf(sc[kf][j] - mnew);
                sc[kf][j] = p;
                sum += p;
            }
            sum += __shfl_xor(sum, 1);
            sum += __shfl_xor(sum, 2);
            sum += __shfl_xor(sum, 4);
            sum += __shfl_xor(sum, 8);
            lrow[j] = lrow[j] * resc + sum;
            #pragma unroll
            for (int df = 0; df < 4; df++) acc_o[df][j] *= resc;
        }

        // P (C-layout) -> per-wave LDS [q][kv] (swizzled), then PV A-frags
        #pragma unroll
        for (int kf = 0; kf < 4; kf++) {
            const int chb = kf * 2 + (lq >> 3);
            #pragma unroll
            for (int j = 0; j < 4; j++) {
                const int prow = g * 4 + j;
                Pw[prow * 64 + ((chb ^ (prow & 7)) << 3) + (lq & 7)] = f2bf(sc[kf][j]);
            }
        }
        // same-wave ds_write -> ds_read: compiler inserts lgkmcnt wait (no barrier needed;
        // Pw region is wave-private)
        #pragma unroll
        for (int c = 0; c < 2; c++) {
            const bf16x8 pa = *reinterpret_cast<const bf16x8*>(&Pw[lq * 64 + (((c * 4 + g) ^ (lq & 7)) << 3)]);
            #pragma unroll
            for (int df = 0; df < 4; df++) {
                const bf16x8 bv = *reinterpret_cast<const bf16x8*>(&Vs[swz64(df * 16 + lq, c * 4 + g)]);
                acc_o[df] = __builtin_amdgcn_mfma_f32_16x16x32_bf16(pa, bv, acc_o[df], 0, 0, 0);
            }
        }
        __syncthreads();
    }

    // epilogue: sink-LSE renorm, divide by l, store bf16
    const float sink = sinks[h];
    #pragma unroll
    for (int j = 0; j < 4; j++) {
        const float lse = mrow[j] + __logf(lrow[j]);
        const float d = sink - lse;
        float f = (d > 20.f) ? d : log1pf(__expf(d));
        if (f > 20.f) f = 20.f;                          // clip(lse-combined, -20, 0)
        const float fac = __expf(-f) / lrow[j];
        const int row = qrow_c + j;
        #pragma unroll
        for (int df = 0; df < 4; df++)
            aout[(size_t)row * DIM_ + h * 64 + df * 16 + lq] = f2bf(acc_o[df][j] * fac);
    }
}

extern "C" void kernel_launch(void* const* d_in, const int* in_sizes, int n_in,
                              void* d_out, int out_size, void* d_ws, size_t ws_size,
                              hipStream_t stream) {
    const float* x     = (const float*)d_in[0];
    const float* rope  = (const float*)d_in[1];
    const float* wq_w  = (const float*)d_in[2];
    const float* wq_b  = (const float*)d_in[3];
    const float* wk_w  = (const float*)d_in[4];
    const float* wk_b  = (const float*)d_in[5];
    const float* wv_w  = (const float*)d_in[6];
    const float* wv_b  = (const float*)d_in[7];
    const float* wo_w  = (const float*)d_in[8];
    const float* wo_b  = (const float*)d_in[9];
    const float* sinks = (const float*)d_in[10];
    float* out = (float*)d_out;

    char* ws = (char*)d_ws;
    unsigned short* xb    = (unsigned short*)(ws);                    //  8 MB  x bf16 [2048][2048]
    unsigned short* wqkv  = (unsigned short*)(ws + (8u  << 20));      // 12 MB  [wq;wk;wv] bf16 [3072][2048]
    unsigned short* wob   = (unsigned short*)(ws + (20u << 20));      //  8 MB  wo bf16 [2048][2048]
    unsigned short* qkbuf = (unsigned short*)(ws + (28u << 20));      // 10 MB  q|k bf16 [2048][2560]
    unsigned short* vtbuf = (unsigned short*)(ws + (38u << 20));      //  2 MB  V^T bf16 [512][2048]
    unsigned short* abuf  = (unsigned short*)(ws + (40u << 20));      //  8 MB  attn out bf16 [2048][2048]
    float*          bcat  = (float*)(ws + (48u << 20));               // 12 KB  concat bias

    cvt_f32_bf16<<<4096, 256, 0, stream>>>(x, xb, 2048 * 2048);
    cvt_f32_bf16<<<4096, 256, 0, stream>>>(wq_w, wqkv, 2048 * 2048);
    cvt_f32_bf16<<<1024, 256, 0, stream>>>(wk_w, wqkv + 4194304, 512 * 2048);
    cvt_f32_bf16<<<1024, 256, 0, stream>>>(wv_w, wqkv + 5242880, 512 * 2048);
    cvt_f32_bf16<<<4096, 256, 0, stream>>>(wo_w, wob, 2048 * 2048);
    build_bias<<<12, 256, 0, stream>>>(wq_b, wk_b, wv_b, bcat);

    gemm_bt<0><<<dim3(24, 16), 256, 0, stream>>>(xb, wqkv, bcat, qkbuf, vtbuf, nullptr, 2048);
    rope_kernel<<<10240, 256, 0, stream>>>(qkbuf, rope);
    attn_kernel<<<dim3(32, 32), 256, 0, stream>>>(qkbuf, vtbuf, sinks, abuf);
    gemm_bt<1><<<dim3(16, 16), 256, 0, stream>>>(abuf, wob, wo_b, nullptr, nullptr, out, 2048);
}

// Round 4
// 293.263 us; speedup vs baseline: 1.2008x; 1.2008x over previous
//
#include <hip/hip_runtime.h>

// Fused GQA attention block for MI355X (gfx950).
// cvt(fp32->bf16, merged) -> QKV GEMM(global_load_lds staging, +bias, q pre-scaled,
// V stored transposed) -> RoPE -> flash attention (paired q-tiles for causal load
// balance, T14 async staging, exp2-domain softmax, sink renorm) -> O-proj GEMM.

#define S_LEN 2048
#define DIM_  2048
#define QK_LD 2560   // q cols 2048 + k cols 512 in the qk buffer

typedef __attribute__((ext_vector_type(8))) __bf16 bf16x8;
typedef __attribute__((ext_vector_type(4))) float f32x4;
typedef __attribute__((ext_vector_type(4))) unsigned short us4;

__device__ __forceinline__ unsigned short f2bf(float f) {
    union { float f; unsigned u; } v; v.f = f;
    unsigned r = v.u + 0x7FFFu + ((v.u >> 16) & 1u);   // RNE
    return (unsigned short)(r >> 16);
}
__device__ __forceinline__ float bf2f(unsigned short u) {
    union { unsigned u; float f; } v; v.u = ((unsigned)u) << 16;
    return v.f;
}

// async global->LDS, 16B per lane; LDS dest = wave-uniform base + lane*16 (m104)
__device__ __forceinline__ void gload_lds16(const void* g, void* l) {
    __builtin_amdgcn_global_load_lds(
        (const __attribute__((address_space(1))) void*)g,
        (__attribute__((address_space(3))) void*)l, 16, 0, 0);
}

// XOR swizzles (16B-chunk permutation within a row, involution):
// [r][32] bf16 tiles (64B rows, 4 chunks):
__device__ __forceinline__ int swz32(int r, int ch) { return r*32 + ((ch ^ ((r >> 1) & 3)) << 3); }
// [r][64] bf16 tiles (128B rows, 8 chunks):
__device__ __forceinline__ int swz64(int r, int ch) { return r*64 + ((ch ^ (r & 7)) << 3); }

// One merged convert kernel: x, wq, wk, wv, wo -> bf16. Region bounds are
// block-aligned (float4 units): 1048576 | 2097152 | 2359296 | 2621440 | 3670016.
__global__ void cvt_all(const float* __restrict__ x,  const float* __restrict__ wq,
                        const float* __restrict__ wk, const float* __restrict__ wv,
                        const float* __restrict__ wo,
                        unsigned short* __restrict__ xb,
                        unsigned short* __restrict__ wqkv,
                        unsigned short* __restrict__ wob) {
    const int i4 = blockIdx.x * 256 + threadIdx.x;
    const float* src; unsigned short* dst; int off;
    if (i4 < 1048576)      { src = x;  dst = xb;             off = i4; }
    else if (i4 < 2097152) { src = wq; dst = wqkv;           off = i4 - 1048576; }
    else if (i4 < 2359296) { src = wk; dst = wqkv + 4194304; off = i4 - 2097152; }
    else if (i4 < 2621440) { src = wv; dst = wqkv + 5242880; off = i4 - 2359296; }
    else                   { src = wo; dst = wob;            off = i4 - 2621440; }
    const float4 v = reinterpret_cast<const float4*>(src)[off];
    us4 o = { f2bf(v.x), f2bf(v.y), f2bf(v.z), f2bf(v.w) };
    reinterpret_cast<us4*>(dst)[off] = o;
}

__global__ void build_bias(const float* __restrict__ qb, const float* __restrict__ kb,
                           const float* __restrict__ vb, float* __restrict__ out) {
    const int i = blockIdx.x * 256 + threadIdx.x;   // 3072 total
    if (i < 2048) out[i] = qb[i];
    else if (i < 2560) out[i] = kb[i - 2048];
    else if (i < 3072) out[i] = vb[i - 2560];
}

// C[m,n] = sum_k A[m,k]*B[n,k] + bias[n]   (B^T-input, 128^2 tile, BK=32,
// global_load_lds staging: linear LDS dest + inverse-swizzled global source)
// MODE 0: QKV epilogue -> q cols pre-scaled by 0.125*log2e, k cols plain, V transposed
// MODE 1: fp32 out (ldc 2048)
template<int MODE>
__global__ __launch_bounds__(256)
void gemm_bt(const unsigned short* __restrict__ A,
             const unsigned short* __restrict__ B,
             const float* __restrict__ bias,
             unsigned short* __restrict__ Cqk,
             unsigned short* __restrict__ Vt,
             float* __restrict__ Cf,
             int K)
{
    __shared__ unsigned short As[128 * 32];
    __shared__ unsigned short Bs[128 * 32];
    const int t = threadIdx.x;
    const int lane = t & 63;
    const int w = t >> 6;
    const int wr = w >> 1, wc = w & 1;
    const int lq = lane & 15;
    const int g = lane >> 4;
    const int m0 = blockIdx.y * 128;
    const int n0 = blockIdx.x * 128;

    const f32x4 z = {0.f, 0.f, 0.f, 0.f};
    f32x4 acc[4][4];
    #pragma unroll
    for (int i = 0; i < 4; i++)
        #pragma unroll
        for (int j = 0; j < 4; j++) acc[i][j] = z;

    for (int k0 = 0; k0 < K; k0 += 32) {
        // stage 128x32 A and B tiles: 512 16B-chunks each, wave w covers
        // chunks [w*128, w*128+128). chunk -> (row r = chunk>>2, phys slot chunk&3);
        // phys slot p holds global logical chunk p ^ ((r>>1)&3)  (matches swz32 reads).
        #pragma unroll
        for (int c = 0; c < 2; c++) {
            const int chunk = w * 128 + c * 64 + lane;
            const int r = chunk >> 2;
            const int chl = (chunk & 3) ^ ((r >> 1) & 3);
            gload_lds16(&A[(size_t)(m0 + r) * K + k0 + (chl << 3)],
                        &As[(size_t)(w * 128 + c * 64) * 8]);
            gload_lds16(&B[(size_t)(n0 + r) * K + k0 + (chl << 3)],
                        &Bs[(size_t)(w * 128 + c * 64) * 8]);
        }
        __syncthreads();   // drains vmcnt before barrier
        bf16x8 a[4], b[4];
        #pragma unroll
        for (int mi = 0; mi < 4; mi++)
            a[mi] = *reinterpret_cast<const bf16x8*>(&As[swz32(wr * 64 + mi * 16 + lq, g)]);
        #pragma unroll
        for (int ni = 0; ni < 4; ni++)
            b[ni] = *reinterpret_cast<const bf16x8*>(&Bs[swz32(wc * 64 + ni * 16 + lq, g)]);
        #pragma unroll
        for (int mi = 0; mi < 4; mi++)
            #pragma unroll
            for (int ni = 0; ni < 4; ni++)
                acc[mi][ni] = __builtin_amdgcn_mfma_f32_16x16x32_bf16(a[mi], b[ni], acc[mi][ni], 0, 0, 0);
        __syncthreads();
    }

    // epilogue: C/D layout col = lane&15, row = (lane>>4)*4 + reg  [m89/m91]
    #pragma unroll
    for (int mi = 0; mi < 4; mi++) {
        const int row0 = m0 + wr * 64 + mi * 16 + g * 4;
        #pragma unroll
        for (int ni = 0; ni < 4; ni++) {
            const int col = n0 + wc * 64 + ni * 16 + lq;
            const float bv = bias[col];
            if (MODE == 1) {
                #pragma unroll
                for (int j = 0; j < 4; j++)
                    Cf[(size_t)(row0 + j) * 2048 + col] = acc[mi][ni][j] + bv;
            } else {
                if (col < 2560) {
                    // fold softmax scale + log2e into q (rope is linear, passes through)
                    const float qs = (col < 2048) ? 0.1803368801f : 1.0f;
                    #pragma unroll
                    for (int j = 0; j < 4; j++)
                        Cqk[(size_t)(row0 + j) * QK_LD + col] = f2bf((acc[mi][ni][j] + bv) * qs);
                } else {
                    us4 pk;
                    #pragma unroll
                    for (int j = 0; j < 4; j++) pk[j] = f2bf(acc[mi][ni][j] + bv);
                    *reinterpret_cast<us4*>(&Vt[(size_t)(col - 2560) * S_LEN + row0]) = pk;
                }
            }
        }
    }
}

// In-place RoPE on q (heads 0..31) and k (heads 32..39) of qk buffer.
__global__ void rope_kernel(unsigned short* __restrict__ qk, const float* __restrict__ rope) {
    const int idx = blockIdx.x * 256 + threadIdx.x;      // 2048*40*32 exact
    const int s = idx / 1280;
    const int rem = idx - s * 1280;
    const int head = rem >> 5;
    const int p = rem & 31;
    const size_t base = (size_t)s * QK_LD + head * 64 + p;
    const float c = rope[s * 128 + p];
    const float sn = rope[s * 128 + 64 + p];
    const float x0 = bf2f(qk[base]);
    const float x1 = bf2f(qk[base + 32]);
    qk[base]      = f2bf(x0 * c - x1 * sn);
    qk[base + 32] = f2bf(x1 * c + x0 * sn);
}

// Flash attention. Causal load balance: block pid handles q-tiles {pid, 31-pid}
// (33 kv-tile iterations each, no tail). 4 waves x 16 q-rows. T14 async staging:
// next tile's K/V global loads issue right after LDS write, land during compute.
__global__ __launch_bounds__(256)
void attn_kernel(const unsigned short* __restrict__ qk,
                 const unsigned short* __restrict__ vt,
                 const float* __restrict__ sinks,
                 unsigned short* __restrict__ aout)
{
    const int pid = blockIdx.x;                  // 0..15
    const int h = blockIdx.y;
    const int hkv = h >> 2;                      // repeat_interleave: kv head = h/4
    const int t = threadIdx.x;
    const int lane = t & 63;
    const int w = t >> 6;
    const int lq = lane & 15;
    const int g = lane >> 4;

    __shared__ unsigned short Ks[64 * 64];       // [kv][d], swizzled
    __shared__ unsigned short Vs[64 * 64];       // [d][kv] (V^T), swizzled
    __shared__ unsigned short Ps[4][16 * 64];    // per-wave P [q][kv], swizzled
    unsigned short* Pw = &Ps[w][0];

    const float sink = sinks[h];
    const f32x4 z = {0.f, 0.f, 0.f, 0.f};

    for (int pass = 0; pass < 2; ++pass) {
        const int qb = pass ? (31 - pid) : pid;
        const int qrow_a = qb * 64 + w * 16 + lq;
        const int qrow_c = qb * 64 + w * 16 + g * 4;

        bf16x8 aq[2];
        #pragma unroll
        for (int c = 0; c < 2; c++)
            aq[c] = *reinterpret_cast<const bf16x8*>(&qk[(size_t)qrow_a * QK_LD + h * 64 + c * 32 + g * 8]);

        f32x4 acc_o[4];
        #pragma unroll
        for (int df = 0; df < 4; df++) acc_o[df] = z;
        float mrow[4] = {-1e30f, -1e30f, -1e30f, -1e30f};
        float lrow[4] = {0.f, 0.f, 0.f, 0.f};

        // prologue: tile 0 into regs
        bf16x8 kreg[2], vreg[2];
        #pragma unroll
        for (int i = 0; i < 2; i++) {
            const int e = i * 256 + t, r = e >> 3, ch = e & 7;
            kreg[i] = *reinterpret_cast<const bf16x8*>(&qk[(size_t)r * QK_LD + 2048 + hkv * 64 + (ch << 3)]);
            vreg[i] = *reinterpret_cast<const bf16x8*>(&vt[(size_t)(hkv * 64 + r) * S_LEN + (ch << 3)]);
        }

        for (int tkv = 0; tkv <= qb; tkv++) {
            __syncthreads();                     // previous tile's readers done
            #pragma unroll
            for (int i = 0; i < 2; i++) {
                const int e = i * 256 + t, r = e >> 3, ch = e & 7;
                *reinterpret_cast<bf16x8*>(&Ks[swz64(r, ch)]) = kreg[i];
                *reinterpret_cast<bf16x8*>(&Vs[swz64(r, ch)]) = vreg[i];
            }
            __syncthreads();
            if (tkv < qb) {                      // T14: issue next loads, overlap compute
                const int kvn = (tkv + 1) * 64;
                #pragma unroll
                for (int i = 0; i < 2; i++) {
                    const int e = i * 256 + t, r = e >> 3, ch = e & 7;
                    kreg[i] = *reinterpret_cast<const bf16x8*>(&qk[(size_t)(kvn + r) * QK_LD + 2048 + hkv * 64 + (ch << 3)]);
                    vreg[i] = *reinterpret_cast<const bf16x8*>(&vt[(size_t)(hkv * 64 + r) * S_LEN + kvn + (ch << 3)]);
                }
            }

            // S = Q'K^T (log2-domain: q pre-scaled by 0.125*log2e)
            f32x4 sc[4];
            #pragma unroll
            for (int kf = 0; kf < 4; kf++) {
                sc[kf] = z;
                #pragma unroll
                for (int c = 0; c < 2; c++) {
                    const bf16x8 bk = *reinterpret_cast<const bf16x8*>(&Ks[swz64(kf * 16 + lq, c * 4 + g)]);
                    sc[kf] = __builtin_amdgcn_mfma_f32_16x16x32_bf16(aq[c], bk, sc[kf], 0, 0, 0);
                }
            }

            if (tkv == qb) {                     // causal mask on the diagonal tile
                const int kv0 = tkv * 64;
                #pragma unroll
                for (int kf = 0; kf < 4; kf++) {
                    const int kvcol = kv0 + kf * 16 + lq;
                    #pragma unroll
                    for (int j = 0; j < 4; j++)
                        if (kvcol > qrow_c + j) sc[kf][j] = -1e30f;
                }
            }

            // online softmax (exp2 domain), rows reduced across the 16-lane group
            #pragma unroll
            for (int j = 0; j < 4; j++) {
                float mx = fmaxf(fmaxf(sc[0][j], sc[1][j]), fmaxf(sc[2][j], sc[3][j]));
                mx = fmaxf(mx, __shfl_xor(mx, 1));
                mx = fmaxf(mx, __shfl_xor(mx, 2));
                mx = fmaxf(mx, __shfl_xor(mx, 4));
                mx = fmaxf(mx, __shfl_xor(mx, 8));
                const float mnew = fmaxf(mrow[j], mx);
                const float resc = exp2f(mrow[j] - mnew);
                mrow[j] = mnew;
                float sum = 0.f;
                #pragma unroll
                for (int kf = 0; kf < 4; kf++) {
                    const float p = exp2f(sc[kf][j] - mnew);
                    sc[kf][j] = p;
                    sum += p;
                }
                sum += __shfl_xor(sum, 1);
                sum += __shfl_xor(sum, 2);
                sum += __shfl_xor(sum, 4);
                sum += __shfl_xor(sum, 8);
                lrow[j] = lrow[j] * resc + sum;
                #pragma unroll
                for (int df = 0; df < 4; df++) acc_o[df][j] *= resc;
            }

            // P (C-layout) -> per-wave LDS [q][kv] (swizzled), then PV A-frags
            #pragma unroll
            for (int kf = 0; kf < 4; kf++) {
                const int chb = kf * 2 + (lq >> 3);
                #pragma unroll
                for (int j = 0; j < 4; j++) {
                    const int prow = g * 4 + j;
                    Pw[prow * 64 + ((chb ^ (prow & 7)) << 3) + (lq & 7)] = f2bf(sc[kf][j]);
                }
            }
            #pragma unroll
            for (int c = 0; c < 2; c++) {
                const bf16x8 pa = *reinterpret_cast<const bf16x8*>(&Pw[lq * 64 + (((c * 4 + g) ^ (lq & 7)) << 3)]);
                #pragma unroll
                for (int df = 0; df < 4; df++) {
                    const bf16x8 bv = *reinterpret_cast<const bf16x8*>(&Vs[swz64(df * 16 + lq, c * 4 + g)]);
                    acc_o[df] = __builtin_amdgcn_mfma_f32_16x16x32_bf16(pa, bv, acc_o[df], 0, 0, 0);
                }
            }
        }

        // epilogue: sink-LSE renorm (convert log2-domain lse to natural), store bf16
        #pragma unroll
        for (int j = 0; j < 4; j++) {
            const float lse = 0.6931471806f * (mrow[j] + log2f(lrow[j]));
            const float d = sink - lse;
            float f = (d > 20.f) ? d : log1pf(__expf(d));
            if (f > 20.f) f = 20.f;
            const float fac = __expf(-f) / lrow[j];
            const int row = qrow_c + j;
            #pragma unroll
            for (int df = 0; df < 4; df++)
                aout[(size_t)row * DIM_ + h * 64 + df * 16 + lq] = f2bf(acc_o[df][j] * fac);
        }
    }
}

extern "C" void kernel_launch(void* const* d_in, const int* in_sizes, int n_in,
                              void* d_out, int out_size, void* d_ws, size_t ws_size,
                              hipStream_t stream) {
    const float* x     = (const float*)d_in[0];
    const float* rope  = (const float*)d_in[1];
    const float* wq_w  = (const float*)d_in[2];
    const float* wq_b  = (const float*)d_in[3];
    const float* wk_w  = (const float*)d_in[4];
    const float* wk_b  = (const float*)d_in[5];
    const float* wv_w  = (const float*)d_in[6];
    const float* wv_b  = (const float*)d_in[7];
    const float* wo_w  = (const float*)d_in[8];
    const float* wo_b  = (const float*)d_in[9];
    const float* sinks = (const float*)d_in[10];
    float* out = (float*)d_out;

    char* ws = (char*)d_ws;
    unsigned short* xb    = (unsigned short*)(ws);                    //  8 MB
    unsigned short* wqkv  = (unsigned short*)(ws + (8u  << 20));      // 12 MB
    unsigned short* wob   = (unsigned short*)(ws + (20u << 20));      //  8 MB
    unsigned short* qkbuf = (unsigned short*)(ws + (28u << 20));      // 10 MB
    unsigned short* vtbuf = (unsigned short*)(ws + (38u << 20));      //  2 MB
    unsigned short* abuf  = (unsigned short*)(ws + (40u << 20));      //  8 MB
    float*          bcat  = (float*)(ws + (48u << 20));               // 12 KB

    cvt_all<<<14336, 256, 0, stream>>>(x, wq_w, wk_w, wv_w, wo_w, xb, wqkv, wob);
    build_bias<<<12, 256, 0, stream>>>(wq_b, wk_b, wv_b, bcat);

    gemm_bt<0><<<dim3(24, 16), 256, 0, stream>>>(xb, wqkv, bcat, qkbuf, vtbuf, nullptr, 2048);
    rope_kernel<<<10240, 256, 0, stream>>>(qkbuf, rope);
    attn_kernel<<<dim3(16, 32), 256, 0, stream>>>(qkbuf, vtbuf, sinks, abuf);
    gemm_bt<1><<<dim3(16, 16), 256, 0, stream>>>(abuf, wob, wo_b, nullptr, nullptr, out, 2048);
}

// Round 5
// 288.035 us; speedup vs baseline: 1.2226x; 1.0181x over previous
//
#include <hip/hip_runtime.h>

// Fused GQA attention block for MI355X (gfx950).
// cvt(fp32->bf16) -> QKV GEMM(2-phase dbuf global_load_lds, +bias, q pre-scaled,
// V transposed) -> RoPE -> flash attention (swapped QK^T: lane-owns-q-row softmax,
// K/V dbuf 1-barrier, longest-first grid, sink renorm) -> O-proj GEMM.

#define S_LEN 2048
#define DIM_  2048
#define QK_LD 2560   // q cols 2048 + k cols 512 in the qk buffer

typedef __attribute__((ext_vector_type(8))) __bf16 bf16x8;
typedef __attribute__((ext_vector_type(4))) float f32x4;
typedef __attribute__((ext_vector_type(4))) unsigned short us4;

__device__ __forceinline__ unsigned short f2bf(float f) {
    union { float f; unsigned u; } v; v.f = f;
    unsigned r = v.u + 0x7FFFu + ((v.u >> 16) & 1u);   // RNE
    return (unsigned short)(r >> 16);
}
__device__ __forceinline__ float bf2f(unsigned short u) {
    union { unsigned u; float f; } v; v.u = ((unsigned)u) << 16;
    return v.f;
}

// async global->LDS, 16B per lane; LDS dest = wave-uniform base + lane*16 (m104)
__device__ __forceinline__ void gload_lds16(const void* g, void* l) {
    __builtin_amdgcn_global_load_lds(
        (const __attribute__((address_space(1))) void*)g,
        (__attribute__((address_space(3))) void*)l, 16, 0, 0);
}

// XOR swizzles (16B-chunk permutation within a row, involution):
__device__ __forceinline__ int swz32(int r, int ch) { return r*32 + ((ch ^ ((r >> 1) & 3)) << 3); }
__device__ __forceinline__ int swz64(int r, int ch) { return r*64 + ((ch ^ (r & 7)) << 3); }

// Merged convert: x, wq, wk, wv, wo -> bf16. Block-aligned float4 bounds.
__global__ void cvt_all(const float* __restrict__ x,  const float* __restrict__ wq,
                        const float* __restrict__ wk, const float* __restrict__ wv,
                        const float* __restrict__ wo,
                        unsigned short* __restrict__ xb,
                        unsigned short* __restrict__ wqkv,
                        unsigned short* __restrict__ wob) {
    const int i4 = blockIdx.x * 256 + threadIdx.x;
    const float* src; unsigned short* dst; int off;
    if (i4 < 1048576)      { src = x;  dst = xb;             off = i4; }
    else if (i4 < 2097152) { src = wq; dst = wqkv;           off = i4 - 1048576; }
    else if (i4 < 2359296) { src = wk; dst = wqkv + 4194304; off = i4 - 2097152; }
    else if (i4 < 2621440) { src = wv; dst = wqkv + 5242880; off = i4 - 2359296; }
    else                   { src = wo; dst = wob;            off = i4 - 2621440; }
    const float4 v = reinterpret_cast<const float4*>(src)[off];
    us4 o = { f2bf(v.x), f2bf(v.y), f2bf(v.z), f2bf(v.w) };
    reinterpret_cast<us4*>(dst)[off] = o;
}

__global__ void build_bias(const float* __restrict__ qb, const float* __restrict__ kb,
                           const float* __restrict__ vb, float* __restrict__ out) {
    const int i = blockIdx.x * 256 + threadIdx.x;   // 3072 total
    if (i < 2048) out[i] = qb[i];
    else if (i < 2560) out[i] = kb[i - 2048];
    else if (i < 3072) out[i] = vb[i - 2560];
}

// C[m,n] = sum_k A[m,k]*B[n,k] + bias[n]. 128^2 tile, BK=32, 2-phase double-buffered
// global_load_lds staging (loads for k+1 issue before compute of k).
// MODE 0: QKV epilogue (q cols pre-scaled 0.125*log2e, V transposed). MODE 1: fp32 out.
template<int MODE>
__global__ __launch_bounds__(256)
void gemm_bt(const unsigned short* __restrict__ A,
             const unsigned short* __restrict__ B,
             const float* __restrict__ bias,
             unsigned short* __restrict__ Cqk,
             unsigned short* __restrict__ Vt,
             float* __restrict__ Cf,
             int K)
{
    __shared__ unsigned short As[2][128 * 32];
    __shared__ unsigned short Bs[2][128 * 32];
    const int t = threadIdx.x;
    const int lane = t & 63;
    const int w = t >> 6;
    const int wr = w >> 1, wc = w & 1;
    const int lq = lane & 15;
    const int g = lane >> 4;
    const int m0 = blockIdx.y * 128;
    const int n0 = blockIdx.x * 128;

    const f32x4 z = {0.f, 0.f, 0.f, 0.f};
    f32x4 acc[4][4];
    #pragma unroll
    for (int i = 0; i < 4; i++)
        #pragma unroll
        for (int j = 0; j < 4; j++) acc[i][j] = z;

    // stage one 128x32 K-slab of A and B into buffer buf
    auto stage = [&](int buf, int k0) {
        #pragma unroll
        for (int c = 0; c < 2; c++) {
            const int chunk = w * 128 + c * 64 + lane;
            const int r = chunk >> 2;
            const int chl = (chunk & 3) ^ ((r >> 1) & 3);   // inverse-swizzled source
            gload_lds16(&A[(size_t)(m0 + r) * K + k0 + (chl << 3)],
                        &As[buf][(size_t)(w * 128 + c * 64) * 8]);
            gload_lds16(&B[(size_t)(n0 + r) * K + k0 + (chl << 3)],
                        &Bs[buf][(size_t)(w * 128 + c * 64) * 8]);
        }
    };

    stage(0, 0);
    __syncthreads();
    const int NIT = K >> 5;
    for (int it = 0; it < NIT; ++it) {
        const int cur = it & 1;
        if (it + 1 < NIT) stage(cur ^ 1, (it + 1) << 5);   // overlap with compute
        bf16x8 a[4], b[4];
        #pragma unroll
        for (int mi = 0; mi < 4; mi++)
            a[mi] = *reinterpret_cast<const bf16x8*>(&As[cur][swz32(wr * 64 + mi * 16 + lq, g)]);
        #pragma unroll
        for (int ni = 0; ni < 4; ni++)
            b[ni] = *reinterpret_cast<const bf16x8*>(&Bs[cur][swz32(wc * 64 + ni * 16 + lq, g)]);
        #pragma unroll
        for (int mi = 0; mi < 4; mi++)
            #pragma unroll
            for (int ni = 0; ni < 4; ni++)
                acc[mi][ni] = __builtin_amdgcn_mfma_f32_16x16x32_bf16(a[mi], b[ni], acc[mi][ni], 0, 0, 0);
        __syncthreads();   // drains this iter's async loads; releases read buffer
    }

    // epilogue: C/D layout col = lane&15, row = (lane>>4)*4 + reg
    #pragma unroll
    for (int mi = 0; mi < 4; mi++) {
        const int row0 = m0 + wr * 64 + mi * 16 + g * 4;
        #pragma unroll
        for (int ni = 0; ni < 4; ni++) {
            const int col = n0 + wc * 64 + ni * 16 + lq;
            const float bv = bias[col];
            if (MODE == 1) {
                #pragma unroll
                for (int j = 0; j < 4; j++)
                    Cf[(size_t)(row0 + j) * 2048 + col] = acc[mi][ni][j] + bv;
            } else {
                if (col < 2560) {
                    const float qs = (col < 2048) ? 0.1803368801f : 1.0f;  // 0.125*log2e
                    #pragma unroll
                    for (int j = 0; j < 4; j++)
                        Cqk[(size_t)(row0 + j) * QK_LD + col] = f2bf((acc[mi][ni][j] + bv) * qs);
                } else {
                    us4 pk;
                    #pragma unroll
                    for (int j = 0; j < 4; j++) pk[j] = f2bf(acc[mi][ni][j] + bv);
                    *reinterpret_cast<us4*>(&Vt[(size_t)(col - 2560) * S_LEN + row0]) = pk;
                }
            }
        }
    }
}

// In-place RoPE on q (heads 0..31) and k (heads 32..39) of qk buffer.
__global__ void rope_kernel(unsigned short* __restrict__ qk, const float* __restrict__ rope) {
    const int idx = blockIdx.x * 256 + threadIdx.x;      // 2048*40*32 exact
    const int s = idx / 1280;
    const int rem = idx - s * 1280;
    const int head = rem >> 5;
    const int p = rem & 31;
    const size_t base = (size_t)s * QK_LD + head * 64 + p;
    const float c = rope[s * 128 + p];
    const float sn = rope[s * 128 + 64 + p];
    const float x0 = bf2f(qk[base]);
    const float x1 = bf2f(qk[base + 32]);
    qk[base]      = f2bf(x0 * c - x1 * sn);
    qk[base + 32] = f2bf(x1 * c + x0 * sn);
}

// Flash attention, swapped QK^T: S^T = mfma(A=K, B=Q) so each lane owns ONE q-row
// (col = lane&15). Row softmax = in-lane over 16 vals + 2 shuffles. PV computes
// O^T = mfma(A=V^T, B=P^T). K/V double-buffered (1 barrier/iter), global->reg
// prefetch overlaps compute. Grid: (32 qb, 32 h), longest tile first.
__global__ __launch_bounds__(256)
void attn_kernel(const unsigned short* __restrict__ qk,
                 const unsigned short* __restrict__ vt,
                 const float* __restrict__ sinks,
                 unsigned short* __restrict__ aout)
{
    const int qb  = 31 - blockIdx.x;             // longest-first dispatch
    const int h   = blockIdx.y;
    const int hkv = h >> 2;
    const int t = threadIdx.x;
    const int lane = t & 63;
    const int w = t >> 6;
    const int lq = lane & 15;
    const int g = lane >> 4;

    __shared__ unsigned short Ks[2][64 * 64];    // [kv][d], swizzled
    __shared__ unsigned short Vs[2][64 * 64];    // [d][kv] (V^T), swizzled
    __shared__ unsigned short Ps[4][16 * 64];    // per-wave P^T as [q][kv], swizzled
    unsigned short* Pw = &Ps[w][0];

    const int qrow = qb * 64 + w * 16 + lq;      // this lane's q row

    bf16x8 aq[2];                                // Q as B-frag: col=lq, k=d=c*32+g*8+e
    #pragma unroll
    for (int c = 0; c < 2; c++)
        aq[c] = *reinterpret_cast<const bf16x8*>(&qk[(size_t)qrow * QK_LD + h * 64 + c * 32 + g * 8]);

    const f32x4 z = {0.f, 0.f, 0.f, 0.f};
    f32x4 acc[4];                                // O^T frags: d = df*16+g*4+j, col q=lq
    #pragma unroll
    for (int df = 0; df < 4; df++) acc[df] = z;
    float m = -1e30f, l = 0.f;

    bf16x8 kreg[2], vreg[2];
    #pragma unroll
    for (int i = 0; i < 2; i++) {                // prologue: tile 0 -> regs
        const int e = i * 256 + t, r = e >> 3, ch = e & 7;
        kreg[i] = *reinterpret_cast<const bf16x8*>(&qk[(size_t)r * QK_LD + 2048 + hkv * 64 + (ch << 3)]);
        vreg[i] = *reinterpret_cast<const bf16x8*>(&vt[(size_t)(hkv * 64 + r) * S_LEN + (ch << 3)]);
    }
    #pragma unroll
    for (int i = 0; i < 2; i++) {                // -> LDS buf 0
        const int e = i * 256 + t, r = e >> 3, ch = e & 7;
        *reinterpret_cast<bf16x8*>(&Ks[0][swz64(r, ch)]) = kreg[i];
        *reinterpret_cast<bf16x8*>(&Vs[0][swz64(r, ch)]) = vreg[i];
    }
    __syncthreads();

    for (int tkv = 0; tkv <= qb; tkv++) {
        const int cur = tkv & 1;
        if (tkv < qb) {                          // prefetch next tile -> regs (overlaps)
            const int kvn = (tkv + 1) * 64;
            #pragma unroll
            for (int i = 0; i < 2; i++) {
                const int e = i * 256 + t, r = e >> 3, ch = e & 7;
                kreg[i] = *reinterpret_cast<const bf16x8*>(&qk[(size_t)(kvn + r) * QK_LD + 2048 + hkv * 64 + (ch << 3)]);
                vreg[i] = *reinterpret_cast<const bf16x8*>(&vt[(size_t)(hkv * 64 + r) * S_LEN + kvn + (ch << 3)]);
            }
        }

        // S^T[kv][q]: sc[f][j] -> kv = f*16+g*4+j (local), q = lq
        f32x4 sc[4];
        #pragma unroll
        for (int f = 0; f < 4; f++) {
            sc[f] = z;
            #pragma unroll
            for (int c = 0; c < 2; c++) {
                const bf16x8 bk = *reinterpret_cast<const bf16x8*>(&Ks[cur][swz64(f * 16 + lq, c * 4 + g)]);
                sc[f] = __builtin_amdgcn_mfma_f32_16x16x32_bf16(bk, aq[c], sc[f], 0, 0, 0);
            }
        }

        if (tkv == qb) {                         // causal mask, diagonal tile only
            const int thr = w * 16 + lq - g * 4; // mask iff f*16 + j > thr
            #pragma unroll
            for (int f = 0; f < 4; f++)
                #pragma unroll
                for (int j = 0; j < 4; j++)
                    if (f * 16 + j > thr) sc[f][j] = -1e30f;
        }

        // online softmax (exp2 domain): in-lane 16 + 2 cross-group shuffles
        float mx = sc[0][0];
        #pragma unroll
        for (int f = 0; f < 4; f++)
            #pragma unroll
            for (int j = 0; j < 4; j++) mx = fmaxf(mx, sc[f][j]);
        mx = fmaxf(mx, __shfl_xor(mx, 16));
        mx = fmaxf(mx, __shfl_xor(mx, 32));
        const float mn = fmaxf(m, mx);
        const float rs = exp2f(m - mn);
        m = mn;
        float s = 0.f;
        #pragma unroll
        for (int f = 0; f < 4; f++)
            #pragma unroll
            for (int j = 0; j < 4; j++) {
                const float p = exp2f(sc[f][j] - mn);
                sc[f][j] = p;
                s += p;
            }
        s += __shfl_xor(s, 16);
        s += __shfl_xor(s, 32);
        l = l * rs + s;
        #pragma unroll
        for (int df = 0; df < 4; df++) acc[df] *= rs;

        // P^T -> Pw [q=lq][kv], 8B-swizzled: kv run f*16+g*4..+3 at 16B-chunk
        // (2f | g>>1) ^ (lq&7), half g&1
        #pragma unroll
        for (int f = 0; f < 4; f++) {
            us4 pk = { f2bf(sc[f][0]), f2bf(sc[f][1]), f2bf(sc[f][2]), f2bf(sc[f][3]) };
            *reinterpret_cast<us4*>(
                &Pw[lq * 64 + ((((f << 1) | (g >> 1)) ^ (lq & 7)) << 3) + ((g & 1) << 2)]) = pk;
        }
        // PV: O^T += V^T * P^T   (B-frag: col=q=lq, k=kv=c*32+g*8+e)
        #pragma unroll
        for (int c = 0; c < 2; c++) {
            const bf16x8 pb = *reinterpret_cast<const bf16x8*>(
                &Pw[lq * 64 + (((c * 4 + g) ^ (lq & 7)) << 3)]);
            #pragma unroll
            for (int df = 0; df < 4; df++) {
                const bf16x8 bv = *reinterpret_cast<const bf16x8*>(&Vs[cur][swz64(df * 16 + lq, c * 4 + g)]);
                acc[df] = __builtin_amdgcn_mfma_f32_16x16x32_bf16(bv, pb, acc[df], 0, 0, 0);
            }
        }

        if (tkv < qb) {                          // write next tile into other buffer
            #pragma unroll
            for (int i = 0; i < 2; i++) {
                const int e = i * 256 + t, r = e >> 3, ch = e & 7;
                *reinterpret_cast<bf16x8*>(&Ks[cur ^ 1][swz64(r, ch)]) = kreg[i];
                *reinterpret_cast<bf16x8*>(&Vs[cur ^ 1][swz64(r, ch)]) = vreg[i];
            }
        }
        __syncthreads();                         // one barrier per tile
    }

    // epilogue: sink-LSE renorm; lane owns q-row qrow, stores 4x us4 (O^T -> O)
    const float sink = sinks[h];
    const float lse = 0.6931471806f * (m + log2f(l));
    const float d = sink - lse;
    float f = (d > 20.f) ? d : log1pf(__expf(d));
    if (f > 20.f) f = 20.f;
    const float fac = __expf(-f) / l;
    #pragma unroll
    for (int df = 0; df < 4; df++) {
        us4 pk = { f2bf(acc[df][0] * fac), f2bf(acc[df][1] * fac),
                   f2bf(acc[df][2] * fac), f2bf(acc[df][3] * fac) };
        *reinterpret_cast<us4*>(&aout[(size_t)qrow * DIM_ + h * 64 + df * 16 + g * 4]) = pk;
    }
}

extern "C" void kernel_launch(void* const* d_in, const int* in_sizes, int n_in,
                              void* d_out, int out_size, void* d_ws, size_t ws_size,
                              hipStream_t stream) {
    const float* x     = (const float*)d_in[0];
    const float* rope  = (const float*)d_in[1];
    const float* wq_w  = (const float*)d_in[2];
    const float* wq_b  = (const float*)d_in[3];
    const float* wk_w  = (const float*)d_in[4];
    const float* wk_b  = (const float*)d_in[5];
    const float* wv_w  = (const float*)d_in[6];
    const float* wv_b  = (const float*)d_in[7];
    const float* wo_w  = (const float*)d_in[8];
    const float* wo_b  = (const float*)d_in[9];
    const float* sinks = (const float*)d_in[10];
    float* out = (float*)d_out;

    char* ws = (char*)d_ws;
    unsigned short* xb    = (unsigned short*)(ws);                    //  8 MB
    unsigned short* wqkv  = (unsigned short*)(ws + (8u  << 20));      // 12 MB
    unsigned short* wob   = (unsigned short*)(ws + (20u << 20));      //  8 MB
    unsigned short* qkbuf = (unsigned short*)(ws + (28u << 20));      // 10 MB
    unsigned short* vtbuf = (unsigned short*)(ws + (38u << 20));      //  2 MB
    unsigned short* abuf  = (unsigned short*)(ws + (40u << 20));      //  8 MB
    float*          bcat  = (float*)(ws + (48u << 20));               // 12 KB

    cvt_all<<<14336, 256, 0, stream>>>(x, wq_w, wk_w, wv_w, wo_w, xb, wqkv, wob);
    build_bias<<<12, 256, 0, stream>>>(wq_b, wk_b, wv_b, bcat);

    gemm_bt<0><<<dim3(24, 16), 256, 0, stream>>>(xb, wqkv, bcat, qkbuf, vtbuf, nullptr, 2048);
    rope_kernel<<<10240, 256, 0, stream>>>(qkbuf, rope);
    attn_kernel<<<dim3(32, 32), 256, 0, stream>>>(qkbuf, vtbuf, sinks, abuf);
    gemm_bt<1><<<dim3(16, 16), 256, 0, stream>>>(abuf, wob, wo_b, nullptr, nullptr, out, 2048);
}

// Round 6
// 288.019 us; speedup vs baseline: 1.2226x; 1.0001x over previous
//
#include <hip/hip_runtime.h>

// Fused GQA attention block for MI355X (gfx950).
// cvt -> QKV GEMM (3-stage counted-vmcnt pipeline) -> RoPE ->
// flash attention (kv-split NC=2, gload_lds staging, swapped QK^T) ->
// combine (sink renorm) -> O-proj GEMM (same pipeline).

#define S_LEN 2048
#define DIM_  2048
#define QK_LD 2560

typedef __attribute__((ext_vector_type(8))) __bf16 bf16x8;
typedef __attribute__((ext_vector_type(4))) float f32x4;
typedef __attribute__((ext_vector_type(4))) unsigned short us4;

__device__ __forceinline__ unsigned short f2bf(float f) {
    union { float f; unsigned u; } v; v.f = f;
    unsigned r = v.u + 0x7FFFu + ((v.u >> 16) & 1u);   // RNE
    return (unsigned short)(r >> 16);
}
__device__ __forceinline__ float bf2f(unsigned short u) {
    union { unsigned u; float f; } v; v.u = ((unsigned)u) << 16;
    return v.f;
}

__device__ __forceinline__ void gload_lds16(const void* g, void* l) {
    __builtin_amdgcn_global_load_lds(
        (const __attribute__((address_space(1))) void*)g,
        (__attribute__((address_space(3))) void*)l, 16, 0, 0);
}

__device__ __forceinline__ int swz32(int r, int ch) { return r*32 + ((ch ^ ((r >> 1) & 3)) << 3); }
__device__ __forceinline__ int swz64(int r, int ch) { return r*64 + ((ch ^ (r & 7)) << 3); }

__global__ void cvt_all(const float* __restrict__ x,  const float* __restrict__ wq,
                        const float* __restrict__ wk, const float* __restrict__ wv,
                        const float* __restrict__ wo,
                        unsigned short* __restrict__ xb,
                        unsigned short* __restrict__ wqkv,
                        unsigned short* __restrict__ wob) {
    const int i4 = blockIdx.x * 256 + threadIdx.x;
    const float* src; unsigned short* dst; int off;
    if (i4 < 1048576)      { src = x;  dst = xb;             off = i4; }
    else if (i4 < 2097152) { src = wq; dst = wqkv;           off = i4 - 1048576; }
    else if (i4 < 2359296) { src = wk; dst = wqkv + 4194304; off = i4 - 2097152; }
    else if (i4 < 2621440) { src = wv; dst = wqkv + 5242880; off = i4 - 2359296; }
    else                   { src = wo; dst = wob;            off = i4 - 2621440; }
    const float4 v = reinterpret_cast<const float4*>(src)[off];
    us4 o = { f2bf(v.x), f2bf(v.y), f2bf(v.z), f2bf(v.w) };
    reinterpret_cast<us4*>(dst)[off] = o;
}

__global__ void build_bias(const float* __restrict__ qb, const float* __restrict__ kb,
                           const float* __restrict__ vb, float* __restrict__ out) {
    const int i = blockIdx.x * 256 + threadIdx.x;
    if (i < 2048) out[i] = qb[i];
    else if (i < 2560) out[i] = kb[i - 2048];
    else if (i < 3072) out[i] = vb[i - 2560];
}

// 128^2 tile, BK=32, 3-stage pipeline: 2 tiles in flight via global_load_lds,
// counted s_waitcnt vmcnt(4) + raw s_barrier (prefetch never drained).
template<int MODE>
__global__ __launch_bounds__(256)
void gemm_bt(const unsigned short* __restrict__ A,
             const unsigned short* __restrict__ B,
             const float* __restrict__ bias,
             unsigned short* __restrict__ Cqk,
             unsigned short* __restrict__ Vt,
             float* __restrict__ Cf,
             int K)
{
    __shared__ unsigned short As[3][128 * 32];
    __shared__ unsigned short Bs[3][128 * 32];
    const int t = threadIdx.x;
    const int lane = t & 63;
    const int w = t >> 6;
    const int wr = w >> 1, wc = w & 1;
    const int lq = lane & 15;
    const int g = lane >> 4;
    const int m0 = blockIdx.y * 128;
    const int n0 = blockIdx.x * 128;

    const f32x4 z = {0.f, 0.f, 0.f, 0.f};
    f32x4 acc[4][4];
    #pragma unroll
    for (int i = 0; i < 4; i++)
        #pragma unroll
        for (int j = 0; j < 4; j++) acc[i][j] = z;

    auto stage = [&](int buf, int k0) {
        #pragma unroll
        for (int c = 0; c < 2; c++) {
            const int chunk = w * 128 + c * 64 + lane;
            const int r = chunk >> 2;
            const int chl = (chunk & 3) ^ ((r >> 1) & 3);   // inverse-swizzled source
            gload_lds16(&A[(size_t)(m0 + r) * K + k0 + (chl << 3)],
                        &As[buf][(size_t)(w * 128 + c * 64) * 8]);
            gload_lds16(&B[(size_t)(n0 + r) * K + k0 + (chl << 3)],
                        &Bs[buf][(size_t)(w * 128 + c * 64) * 8]);
        }
    };

    const int NIT = K >> 5;
    stage(0, 0);
    stage(1, 32);
    for (int it = 0; it < NIT; ++it) {
        // wait own tile-it loads (oldest 4 of <=8 outstanding), then publish
        if (it + 1 < NIT) asm volatile("s_waitcnt vmcnt(4)" ::: "memory");
        else              asm volatile("s_waitcnt vmcnt(0)" ::: "memory");
        __builtin_amdgcn_s_barrier();
        if (it + 2 < NIT) stage((it + 2) % 3, (it + 2) << 5);
        const int cur = it % 3;
        bf16x8 a[4], b[4];
        #pragma unroll
        for (int mi = 0; mi < 4; mi++)
            a[mi] = *reinterpret_cast<const bf16x8*>(&As[cur][swz32(wr * 64 + mi * 16 + lq, g)]);
        #pragma unroll
        for (int ni = 0; ni < 4; ni++)
            b[ni] = *reinterpret_cast<const bf16x8*>(&Bs[cur][swz32(wc * 64 + ni * 16 + lq, g)]);
        #pragma unroll
        for (int mi = 0; mi < 4; mi++)
            #pragma unroll
            for (int ni = 0; ni < 4; ni++)
                acc[mi][ni] = __builtin_amdgcn_mfma_f32_16x16x32_bf16(a[mi], b[ni], acc[mi][ni], 0, 0, 0);
    }

    #pragma unroll
    for (int mi = 0; mi < 4; mi++) {
        const int row0 = m0 + wr * 64 + mi * 16 + g * 4;
        #pragma unroll
        for (int ni = 0; ni < 4; ni++) {
            const int col = n0 + wc * 64 + ni * 16 + lq;
            const float bv = bias[col];
            if (MODE == 1) {
                #pragma unroll
                for (int j = 0; j < 4; j++)
                    Cf[(size_t)(row0 + j) * 2048 + col] = acc[mi][ni][j] + bv;
            } else {
                if (col < 2560) {
                    const float qs = (col < 2048) ? 0.1803368801f : 1.0f;  // 0.125*log2e
                    #pragma unroll
                    for (int j = 0; j < 4; j++)
                        Cqk[(size_t)(row0 + j) * QK_LD + col] = f2bf((acc[mi][ni][j] + bv) * qs);
                } else {
                    us4 pk;
                    #pragma unroll
                    for (int j = 0; j < 4; j++) pk[j] = f2bf(acc[mi][ni][j] + bv);
                    *reinterpret_cast<us4*>(&Vt[(size_t)(col - 2560) * S_LEN + row0]) = pk;
                }
            }
        }
    }
}

__global__ void rope_kernel(unsigned short* __restrict__ qk, const float* __restrict__ rope) {
    const int idx = blockIdx.x * 256 + threadIdx.x;
    const int s = idx / 1280;
    const int rem = idx - s * 1280;
    const int head = rem >> 5;
    const int p = rem & 31;
    const size_t base = (size_t)s * QK_LD + head * 64 + p;
    const float c = rope[s * 128 + p];
    const float sn = rope[s * 128 + 64 + p];
    const float x0 = bf2f(qk[base]);
    const float x1 = bf2f(qk[base + 32]);
    qk[base]      = f2bf(x0 * c - x1 * sn);
    qk[base + 32] = f2bf(x1 * c + x0 * sn);
}

// Flash attention, kv-split NC=2: block (qb, c) processes kv tiles t ≡ c (mod 2),
// t <= qb. Swapped QK^T (lane owns q-row). K/V staged via global_load_lds
// (pre-swizzled source, dbuf, vmcnt(0)+raw barrier once per tile). Partials
// (unnormalized acc bf16, m/l fp32) written for the combine pass.
__global__ __launch_bounds__(256)
void attn_kernel(const unsigned short* __restrict__ qk,
                 const unsigned short* __restrict__ vt,
                 unsigned short* __restrict__ pacc,
                 float* __restrict__ pml)
{
    const int bx = blockIdx.x;                   // 0..63
    const int c = bx & 1;
    const int qb = 31 - (bx >> 1);               // longest-first
    const int h = blockIdx.y;
    const int hkv = h >> 2;
    const int t = threadIdx.x;
    const int lane = t & 63;
    const int w = t >> 6;
    const int lq = lane & 15;
    const int g = lane >> 4;

    __shared__ unsigned short Ks[2][64 * 64];
    __shared__ unsigned short Vs[2][64 * 64];
    __shared__ unsigned short Ps[4][16 * 64];
    unsigned short* Pw = &Ps[w][0];

    const int qrow = qb * 64 + w * 16 + lq;

    bf16x8 aq[2];
    #pragma unroll
    for (int cc = 0; cc < 2; cc++)
        aq[cc] = *reinterpret_cast<const bf16x8*>(&qk[(size_t)qrow * QK_LD + h * 64 + cc * 32 + g * 8]);
    {   // force Q loads resolved pre-loop so compiler's wait doesn't land in-loop
        const uint4 u0 = reinterpret_cast<const uint4&>(aq[0]);
        const uint4 u1 = reinterpret_cast<const uint4&>(aq[1]);
        asm volatile("" :: "v"(u0.x), "v"(u0.y), "v"(u0.z), "v"(u0.w),
                           "v"(u1.x), "v"(u1.y), "v"(u1.z), "v"(u1.w));
    }

    const f32x4 z = {0.f, 0.f, 0.f, 0.f};
    f32x4 acc[4];
    #pragma unroll
    for (int df = 0; df < 4; df++) acc[df] = z;
    float m = -1e30f, l = 0.f;

    // stage tile tv (kv0 = tv*64) into buffer buf: 512 chunks per array,
    // linear LDS dest (wave-uniform base), inverse-swizzled global source.
    auto stage = [&](int buf, int tv) {
        const int kv0 = tv * 64;
        #pragma unroll
        for (int i = 0; i < 2; i++) {
            const int chunk = i * 256 + w * 64 + lane;
            const int r = chunk >> 3;
            const int chl = (chunk & 7) ^ (r & 7);
            gload_lds16(&qk[(size_t)(kv0 + r) * QK_LD + 2048 + hkv * 64 + (chl << 3)],
                        &Ks[buf][(size_t)(i * 256 + w * 64) * 8]);
            gload_lds16(&vt[(size_t)(hkv * 64 + r) * S_LEN + kv0 + (chl << 3)],
                        &Vs[buf][(size_t)(i * 256 + w * 64) * 8]);
        }
    };

    const int ntile = (qb >= c) ? ((qb - c) >> 1) + 1 : 0;
    if (ntile > 0) stage(0, c);
    int cur = 0;
    for (int i = 0; i < ntile; ++i) {
        const int tv = c + 2 * i;
        asm volatile("s_waitcnt vmcnt(0)" ::: "memory");  // tile-i loads landed
        __builtin_amdgcn_s_barrier();                     // publish; prev readers done
        if (i + 1 < ntile) stage(cur ^ 1, tv + 2);        // flies under compute

        f32x4 sc[4];
        #pragma unroll
        for (int f = 0; f < 4; f++) {
            sc[f] = z;
            #pragma unroll
            for (int cc = 0; cc < 2; cc++) {
                const bf16x8 bk = *reinterpret_cast<const bf16x8*>(&Ks[cur][swz64(f * 16 + lq, cc * 4 + g)]);
                sc[f] = __builtin_amdgcn_mfma_f32_16x16x32_bf16(bk, aq[cc], sc[f], 0, 0, 0);
            }
        }

        if (tv == qb) {
            const int thr = w * 16 + lq - g * 4;
            #pragma unroll
            for (int f = 0; f < 4; f++)
                #pragma unroll
                for (int j = 0; j < 4; j++)
                    if (f * 16 + j > thr) sc[f][j] = -1e30f;
        }

        float mx = sc[0][0];
        #pragma unroll
        for (int f = 0; f < 4; f++)
            #pragma unroll
            for (int j = 0; j < 4; j++) mx = fmaxf(mx, sc[f][j]);
        mx = fmaxf(mx, __shfl_xor(mx, 16));
        mx = fmaxf(mx, __shfl_xor(mx, 32));
        const float mn = fmaxf(m, mx);
        const float rs = exp2f(m - mn);
        m = mn;
        float s = 0.f;
        #pragma unroll
        for (int f = 0; f < 4; f++)
            #pragma unroll
            for (int j = 0; j < 4; j++) {
                const float p = exp2f(sc[f][j] - mn);
                sc[f][j] = p;
                s += p;
            }
        s += __shfl_xor(s, 16);
        s += __shfl_xor(s, 32);
        l = l * rs + s;
        #pragma unroll
        for (int df = 0; df < 4; df++) acc[df] *= rs;

        #pragma unroll
        for (int f = 0; f < 4; f++) {
            us4 pk = { f2bf(sc[f][0]), f2bf(sc[f][1]), f2bf(sc[f][2]), f2bf(sc[f][3]) };
            *reinterpret_cast<us4*>(
                &Pw[lq * 64 + ((((f << 1) | (g >> 1)) ^ (lq & 7)) << 3) + ((g & 1) << 2)]) = pk;
        }
        #pragma unroll
        for (int cc = 0; cc < 2; cc++) {
            const bf16x8 pb = *reinterpret_cast<const bf16x8*>(
                &Pw[lq * 64 + (((cc * 4 + g) ^ (lq & 7)) << 3)]);
            #pragma unroll
            for (int df = 0; df < 4; df++) {
                const bf16x8 bv = *reinterpret_cast<const bf16x8*>(&Vs[cur][swz64(df * 16 + lq, cc * 4 + g)]);
                acc[df] = __builtin_amdgcn_mfma_f32_16x16x32_bf16(bv, pb, acc[df], 0, 0, 0);
            }
        }
        cur ^= 1;
    }

    // partial store: acc (unnormalized) bf16, m/l fp32
    const size_t rbase = ((size_t)(h * 2 + c) * 2048 + qrow);
    #pragma unroll
    for (int df = 0; df < 4; df++) {
        us4 pk = { f2bf(acc[df][0]), f2bf(acc[df][1]), f2bf(acc[df][2]), f2bf(acc[df][3]) };
        *reinterpret_cast<us4*>(&pacc[rbase * 64 + df * 16 + g * 4]) = pk;
    }
    if (g == 0) {
        pml[rbase * 2]     = m;
        pml[rbase * 2 + 1] = l;
    }
}

// Combine NC=2 partials + sink-LSE renorm -> abuf bf16.
__global__ void attn_combine(const unsigned short* __restrict__ pacc,
                             const float* __restrict__ pml,
                             const float* __restrict__ sinks,
                             unsigned short* __restrict__ abuf) {
    const int idx = blockIdx.x * 256 + threadIdx.x;      // 2048*32*4
    const int q4 = idx & 3;
    const int row = (idx >> 2) & 2047;
    const int h = idx >> 13;
    const size_t r0 = (size_t)(h * 2 + 0) * 2048 + row;
    const size_t r1 = (size_t)(h * 2 + 1) * 2048 + row;
    const float m0 = pml[r0 * 2], l0 = pml[r0 * 2 + 1];
    const float m1 = pml[r1 * 2], l1 = pml[r1 * 2 + 1];
    const float M = fmaxf(m0, m1);
    const float w0 = exp2f(m0 - M), w1 = exp2f(m1 - M);
    const float L = l0 * w0 + l1 * w1;
    const float lse = 0.6931471806f * (M + log2f(L));
    const float d = sinks[h] - lse;
    float f = (d > 20.f) ? d : log1pf(__expf(d));
    if (f > 20.f) f = 20.f;
    const float fac = __expf(-f) / L;
    const unsigned short* a0 = &pacc[r0 * 64 + q4 * 16];
    const unsigned short* a1 = &pacc[r1 * 64 + q4 * 16];
    unsigned short* dst = &abuf[(size_t)row * DIM_ + h * 64 + q4 * 16];
    #pragma unroll
    for (int k = 0; k < 4; k++) {
        const us4 x0 = *reinterpret_cast<const us4*>(&a0[k * 4]);
        const us4 x1 = *reinterpret_cast<const us4*>(&a1[k * 4]);
        us4 r;
        #pragma unroll
        for (int j = 0; j < 4; j++)
            r[j] = f2bf((bf2f(x0[j]) * w0 + bf2f(x1[j]) * w1) * fac);
        *reinterpret_cast<us4*>(&dst[k * 4]) = r;
    }
}

extern "C" void kernel_launch(void* const* d_in, const int* in_sizes, int n_in,
                              void* d_out, int out_size, void* d_ws, size_t ws_size,
                              hipStream_t stream) {
    const float* x     = (const float*)d_in[0];
    const float* rope  = (const float*)d_in[1];
    const float* wq_w  = (const float*)d_in[2];
    const float* wq_b  = (const float*)d_in[3];
    const float* wk_w  = (const float*)d_in[4];
    const float* wk_b  = (const float*)d_in[5];
    const float* wv_w  = (const float*)d_in[6];
    const float* wv_b  = (const float*)d_in[7];
    const float* wo_w  = (const float*)d_in[8];
    const float* wo_b  = (const float*)d_in[9];
    const float* sinks = (const float*)d_in[10];
    float* out = (float*)d_out;

    char* ws = (char*)d_ws;
    unsigned short* xb    = (unsigned short*)(ws);                    //  8 MB (dead after QKV gemm)
    unsigned short* wqkv  = (unsigned short*)(ws + (8u  << 20));      // 12 MB (dead after QKV gemm)
    unsigned short* wob   = (unsigned short*)(ws + (20u << 20));      //  8 MB
    unsigned short* qkbuf = (unsigned short*)(ws + (28u << 20));      // 10 MB
    unsigned short* vtbuf = (unsigned short*)(ws + (38u << 20));      //  2 MB
    unsigned short* abuf  = (unsigned short*)(ws + (40u << 20));      //  8 MB
    float*          bcat  = (float*)(ws + (48u << 20));               // 12 KB
    // attn partials reuse dead [0,20MB): pacc 16 MB @0, pml 2 MB @16MB
    unsigned short* pacc  = (unsigned short*)(ws);
    float*          pml   = (float*)(ws + (16u << 20));

    cvt_all<<<14336, 256, 0, stream>>>(x, wq_w, wk_w, wv_w, wo_w, xb, wqkv, wob);
    build_bias<<<12, 256, 0, stream>>>(wq_b, wk_b, wv_b, bcat);

    gemm_bt<0><<<dim3(24, 16), 256, 0, stream>>>(xb, wqkv, bcat, qkbuf, vtbuf, nullptr, 2048);
    rope_kernel<<<10240, 256, 0, stream>>>(qkbuf, rope);
    attn_kernel<<<dim3(64, 32), 256, 0, stream>>>(qkbuf, vtbuf, pacc, pml);
    attn_combine<<<1024, 256, 0, stream>>>(pacc, pml, sinks, abuf);
    gemm_bt<1><<<dim3(16, 16), 256, 0, stream>>>(abuf, wob, wo_b, nullptr, nullptr, out, 2048);
}

// Round 7
// 252.599 us; speedup vs baseline: 1.3941x; 1.1402x over previous
//
#include <hip/hip_runtime.h>

// Fused GQA attention block for MI355X (gfx950).
// cvt -> QKV GEMM (K-split z=2, bf16 partials, 2-stage dbuf gload_lds) ->
// rope_combine (partial-sum+bias+scale+RoPE+V-transpose) ->
// flash attention (kv-split NC=2, CU-balanced grid, swapped QK^T) ->
// attn_combine (sink renorm) -> O-proj GEMM (K-split) -> o_combine.

#define S_LEN 2048
#define DIM_  2048
#define QK_LD 2560

typedef __attribute__((ext_vector_type(8))) __bf16 bf16x8;
typedef __attribute__((ext_vector_type(4))) float f32x4;
typedef __attribute__((ext_vector_type(4))) unsigned short us4;

__device__ __forceinline__ unsigned short f2bf(float f) {
    const __bf16 h = (__bf16)f;                 // hardware RNE (v_cvt_pk_bf16_f32)
    return __builtin_bit_cast(unsigned short, h);
}
__device__ __forceinline__ float bf2f(unsigned short u) {
    union { unsigned u; float f; } v; v.u = ((unsigned)u) << 16;
    return v.f;
}

__device__ __forceinline__ void gload_lds16(const void* g, void* l) {
    __builtin_amdgcn_global_load_lds(
        (const __attribute__((address_space(1))) void*)g,
        (__attribute__((address_space(3))) void*)l, 16, 0, 0);
}

__device__ __forceinline__ int swz32(int r, int ch) { return r*32 + ((ch ^ ((r >> 1) & 3)) << 3); }
__device__ __forceinline__ int swz64(int r, int ch) { return r*64 + ((ch ^ (r & 7)) << 3); }

__global__ void cvt_all(const float* __restrict__ x,  const float* __restrict__ wq,
                        const float* __restrict__ wk, const float* __restrict__ wv,
                        const float* __restrict__ wo,
                        unsigned short* __restrict__ xb,
                        unsigned short* __restrict__ wqkv,
                        unsigned short* __restrict__ wob) {
    const int i4 = blockIdx.x * 256 + threadIdx.x;
    const float* src; unsigned short* dst; int off;
    if (i4 < 1048576)      { src = x;  dst = xb;             off = i4; }
    else if (i4 < 2097152) { src = wq; dst = wqkv;           off = i4 - 1048576; }
    else if (i4 < 2359296) { src = wk; dst = wqkv + 4194304; off = i4 - 2097152; }
    else if (i4 < 2621440) { src = wv; dst = wqkv + 5242880; off = i4 - 2359296; }
    else                   { src = wo; dst = wob;            off = i4 - 2621440; }
    const float4 v = reinterpret_cast<const float4*>(src)[off];
    us4 o = { f2bf(v.x), f2bf(v.y), f2bf(v.z), f2bf(v.w) };
    reinterpret_cast<us4*>(dst)[off] = o;
}

__global__ void build_bias(const float* __restrict__ qb, const float* __restrict__ kb,
                           const float* __restrict__ vb, float* __restrict__ out) {
    const int i = blockIdx.x * 256 + threadIdx.x;
    if (i < 2048) out[i] = qb[i];
    else if (i < 2560) out[i] = kb[i - 2048];
    else if (i < 3072) out[i] = vb[i - 2560];
}

// P[z][m][n] = sum_{k in z-half} A[m,k]*B[n,k], bf16 partial. 128^2 tile, BK=32,
// 2-stage dbuf via global_load_lds: stage(i+1) issued right after the barrier,
// lands during compute(i); one vmcnt(0)+barrier per K-step. K-split doubles
// blocks -> 2-3 blocks/CU so TLP hides the residual latency.
__global__ __launch_bounds__(256)
void gemm_part(const unsigned short* __restrict__ A,
               const unsigned short* __restrict__ B,
               unsigned short* __restrict__ P,
               int K, int ldc)
{
    __shared__ unsigned short As[2][128 * 32];
    __shared__ unsigned short Bs[2][128 * 32];
    const int t = threadIdx.x;
    const int lane = t & 63;
    const int w = t >> 6;
    const int wr = w >> 1, wc = w & 1;
    const int lq = lane & 15;
    const int g = lane >> 4;
    const int m0 = blockIdx.y * 128;
    const int n0 = blockIdx.x * 128;
    const int kbase = blockIdx.z * (K >> 1);
    const size_t zoff = (size_t)blockIdx.z * 2048 * ldc;

    const f32x4 z = {0.f, 0.f, 0.f, 0.f};
    f32x4 acc[4][4];
    #pragma unroll
    for (int i = 0; i < 4; i++)
        #pragma unroll
        for (int j = 0; j < 4; j++) acc[i][j] = z;

    auto stage = [&](int buf, int k0) {
        #pragma unroll
        for (int c = 0; c < 2; c++) {
            const int chunk = w * 128 + c * 64 + lane;
            const int r = chunk >> 2;
            const int chl = (chunk & 3) ^ ((r >> 1) & 3);   // inverse-swizzled source
            gload_lds16(&A[(size_t)(m0 + r) * K + kbase + k0 + (chl << 3)],
                        &As[buf][(size_t)(w * 128 + c * 64) * 8]);
            gload_lds16(&B[(size_t)(n0 + r) * K + kbase + k0 + (chl << 3)],
                        &Bs[buf][(size_t)(w * 128 + c * 64) * 8]);
        }
    };

    const int NIT = K >> 6;                      // (K/2)/32
    stage(0, 0);
    for (int it = 0; it < NIT; ++it) {
        const int cur = it & 1;
        asm volatile("s_waitcnt vmcnt(0)" ::: "memory");   // tile-it loads landed
        __builtin_amdgcn_s_barrier();                      // prev compute done too
        if (it + 1 < NIT) stage(cur ^ 1, (it + 1) << 5);   // overlaps compute below
        bf16x8 a[4], b[4];
        #pragma unroll
        for (int mi = 0; mi < 4; mi++)
            a[mi] = *reinterpret_cast<const bf16x8*>(&As[cur][swz32(wr * 64 + mi * 16 + lq, g)]);
        #pragma unroll
        for (int ni = 0; ni < 4; ni++)
            b[ni] = *reinterpret_cast<const bf16x8*>(&Bs[cur][swz32(wc * 64 + ni * 16 + lq, g)]);
        #pragma unroll
        for (int mi = 0; mi < 4; mi++)
            #pragma unroll
            for (int ni = 0; ni < 4; ni++)
                acc[mi][ni] = __builtin_amdgcn_mfma_f32_16x16x32_bf16(a[mi], b[ni], acc[mi][ni], 0, 0, 0);
    }

    // bf16 partial store; C/D layout col = lane&15, row = (lane>>4)*4 + reg
    #pragma unroll
    for (int mi = 0; mi < 4; mi++) {
        const int row0 = m0 + wr * 64 + mi * 16 + g * 4;
        #pragma unroll
        for (int ni = 0; ni < 4; ni++) {
            const int col = n0 + wc * 64 + ni * 16 + lq;
            #pragma unroll
            for (int j = 0; j < 4; j++)
                P[zoff + (size_t)(row0 + j) * ldc + col] = f2bf(acc[mi][ni][j]);
        }
    }
}

// Combine QKV partials + bias, apply RoPE (+0.125*log2e fold into q), build
// qkbuf [2048][2560] and transposed V vtbuf [512][2048].
__global__ void rope_combine(const unsigned short* __restrict__ pq,
                             const float* __restrict__ bias,
                             const float* __restrict__ rope,
                             unsigned short* __restrict__ qk,
                             unsigned short* __restrict__ vt)
{
    const int idx = blockIdx.x * 256 + threadIdx.x;
    if (idx < 2621440) {                         // q/k rope: 2048 * 40 heads * 32 pairs
        const int s = idx / 1280;
        const int rem = idx - s * 1280;
        const int head = rem >> 5;
        const int p = rem & 31;
        const int col0 = head * 64 + p;
        const int col1 = col0 + 32;
        const size_t r0 = (size_t)s * 3072;
        const float v0 = bf2f(pq[r0 + col0]) + bf2f(pq[6291456 + r0 + col0]) + bias[col0];
        const float v1 = bf2f(pq[r0 + col1]) + bf2f(pq[6291456 + r0 + col1]) + bias[col1];
        const float c = rope[s * 128 + p];
        const float sn = rope[s * 128 + 64 + p];
        const float qs = (head < 32) ? 0.1803368801f : 1.0f;   // 0.125*log2e on q only
        qk[(size_t)s * QK_LD + col0] = f2bf((v0 * c - v1 * sn) * qs);
        qk[(size_t)s * QK_LD + col1] = f2bf((v1 * c + v0 * sn) * qs);
    } else {                                     // v: combine + transpose, 512 d x 512 s4
        const int i = idx - 2621440;
        const int d = i >> 9;
        const int s4 = (i & 511) << 2;
        const float bv = bias[2560 + d];
        us4 o;
        #pragma unroll
        for (int j = 0; j < 4; j++) {
            const size_t r = (size_t)(s4 + j) * 3072 + 2560 + d;
            o[j] = f2bf(bf2f(pq[r]) + bf2f(pq[6291456 + r]) + bv);
        }
        *reinterpret_cast<us4*>(&vt[(size_t)d * S_LEN + s4]) = o;
    }
}

// Flash attention, kv-split NC=2. Grid (32 h, 64 qbc): consecutive block ids sweep
// h, so each CU's blocks span different qb values (per-CU work balanced).
__global__ __launch_bounds__(256)
void attn_kernel(const unsigned short* __restrict__ qk,
                 const unsigned short* __restrict__ vt,
                 unsigned short* __restrict__ pacc,
                 float* __restrict__ pml)
{
    const int h = blockIdx.x;
    const int by = blockIdx.y;                   // 0..63
    const int c = by & 1;
    const int qb = 31 - (by >> 1);
    const int hkv = h >> 2;
    const int t = threadIdx.x;
    const int lane = t & 63;
    const int w = t >> 6;
    const int lq = lane & 15;
    const int g = lane >> 4;

    __shared__ unsigned short Ks[2][64 * 64];
    __shared__ unsigned short Vs[2][64 * 64];
    __shared__ unsigned short Ps[4][16 * 64];
    unsigned short* Pw = &Ps[w][0];

    const int qrow = qb * 64 + w * 16 + lq;

    bf16x8 aq[2];
    #pragma unroll
    for (int cc = 0; cc < 2; cc++)
        aq[cc] = *reinterpret_cast<const bf16x8*>(&qk[(size_t)qrow * QK_LD + h * 64 + cc * 32 + g * 8]);
    {   // force Q loads resolved pre-loop
        const uint4 u0 = reinterpret_cast<const uint4&>(aq[0]);
        const uint4 u1 = reinterpret_cast<const uint4&>(aq[1]);
        asm volatile("" :: "v"(u0.x), "v"(u0.y), "v"(u0.z), "v"(u0.w),
                           "v"(u1.x), "v"(u1.y), "v"(u1.z), "v"(u1.w));
    }

    const f32x4 z = {0.f, 0.f, 0.f, 0.f};
    f32x4 acc[4];
    #pragma unroll
    for (int df = 0; df < 4; df++) acc[df] = z;
    float m = -1e30f, l = 0.f;

    auto stage = [&](int buf, int tv) {
        const int kv0 = tv * 64;
        #pragma unroll
        for (int i = 0; i < 2; i++) {
            const int chunk = i * 256 + w * 64 + lane;
            const int r = chunk >> 3;
            const int chl = (chunk & 7) ^ (r & 7);
            gload_lds16(&qk[(size_t)(kv0 + r) * QK_LD + 2048 + hkv * 64 + (chl << 3)],
                        &Ks[buf][(size_t)(i * 256 + w * 64) * 8]);
            gload_lds16(&vt[(size_t)(hkv * 64 + r) * S_LEN + kv0 + (chl << 3)],
                        &Vs[buf][(size_t)(i * 256 + w * 64) * 8]);
        }
    };

    const int ntile = (qb >= c) ? ((qb - c) >> 1) + 1 : 0;
    if (ntile > 0) stage(0, c);
    int cur = 0;
    for (int i = 0; i < ntile; ++i) {
        const int tv = c + 2 * i;
        asm volatile("s_waitcnt vmcnt(0)" ::: "memory");
        __builtin_amdgcn_s_barrier();
        if (i + 1 < ntile) stage(cur ^ 1, tv + 2);

        f32x4 sc[4];
        #pragma unroll
        for (int f = 0; f < 4; f++) {
            sc[f] = z;
            #pragma unroll
            for (int cc = 0; cc < 2; cc++) {
                const bf16x8 bk = *reinterpret_cast<const bf16x8*>(&Ks[cur][swz64(f * 16 + lq, cc * 4 + g)]);
                sc[f] = __builtin_amdgcn_mfma_f32_16x16x32_bf16(bk, aq[cc], sc[f], 0, 0, 0);
            }
        }

        if (tv == qb) {
            const int thr = w * 16 + lq - g * 4;
            #pragma unroll
            for (int f = 0; f < 4; f++)
                #pragma unroll
                for (int j = 0; j < 4; j++)
                    if (f * 16 + j > thr) sc[f][j] = -1e30f;
        }

        float mx = sc[0][0];
        #pragma unroll
        for (int f = 0; f < 4; f++)
            #pragma unroll
            for (int j = 0; j < 4; j++) mx = fmaxf(mx, sc[f][j]);
        mx = fmaxf(mx, __shfl_xor(mx, 16));
        mx = fmaxf(mx, __shfl_xor(mx, 32));
        const float mn = fmaxf(m, mx);
        const float rs = exp2f(m - mn);
        m = mn;
        float s = 0.f;
        #pragma unroll
        for (int f = 0; f < 4; f++)
            #pragma unroll
            for (int j = 0; j < 4; j++) {
                const float p = exp2f(sc[f][j] - mn);
                sc[f][j] = p;
                s += p;
            }
        s += __shfl_xor(s, 16);
        s += __shfl_xor(s, 32);
        l = l * rs + s;
        #pragma unroll
        for (int df = 0; df < 4; df++) acc[df] *= rs;

        #pragma unroll
        for (int f = 0; f < 4; f++) {
            us4 pk = { f2bf(sc[f][0]), f2bf(sc[f][1]), f2bf(sc[f][2]), f2bf(sc[f][3]) };
            *reinterpret_cast<us4*>(
                &Pw[lq * 64 + ((((f << 1) | (g >> 1)) ^ (lq & 7)) << 3) + ((g & 1) << 2)]) = pk;
        }
        #pragma unroll
        for (int cc = 0; cc < 2; cc++) {
            const bf16x8 pb = *reinterpret_cast<const bf16x8*>(
                &Pw[lq * 64 + (((cc * 4 + g) ^ (lq & 7)) << 3)]);
            #pragma unroll
            for (int df = 0; df < 4; df++) {
                const bf16x8 bv = *reinterpret_cast<const bf16x8*>(&Vs[cur][swz64(df * 16 + lq, cc * 4 + g)]);
                acc[df] = __builtin_amdgcn_mfma_f32_16x16x32_bf16(bv, pb, acc[df], 0, 0, 0);
            }
        }
        cur ^= 1;
    }

    const size_t rbase = ((size_t)(h * 2 + c) * 2048 + qrow);
    #pragma unroll
    for (int df = 0; df < 4; df++) {
        us4 pk = { f2bf(acc[df][0]), f2bf(acc[df][1]), f2bf(acc[df][2]), f2bf(acc[df][3]) };
        *reinterpret_cast<us4*>(&pacc[rbase * 64 + df * 16 + g * 4]) = pk;
    }
    if (g == 0) {
        pml[rbase * 2]     = m;
        pml[rbase * 2 + 1] = l;
    }
}

__global__ void attn_combine(const unsigned short* __restrict__ pacc,
                             const float* __restrict__ pml,
                             const float* __restrict__ sinks,
                             unsigned short* __restrict__ abuf) {
    const int idx = blockIdx.x * 256 + threadIdx.x;      // 2048*32*4
    const int q4 = idx & 3;
    const int row = (idx >> 2) & 2047;
    const int h = idx >> 13;
    const size_t r0 = (size_t)(h * 2 + 0) * 2048 + row;
    const size_t r1 = (size_t)(h * 2 + 1) * 2048 + row;
    const float m0 = pml[r0 * 2], l0 = pml[r0 * 2 + 1];
    const float m1 = pml[r1 * 2], l1 = pml[r1 * 2 + 1];
    const float M = fmaxf(m0, m1);
    const float w0 = exp2f(m0 - M), w1 = exp2f(m1 - M);
    const float L = l0 * w0 + l1 * w1;
    const float lse = 0.6931471806f * (M + log2f(L));
    const float d = sinks[h] - lse;
    float f = (d > 20.f) ? d : log1pf(__expf(d));
    if (f > 20.f) f = 20.f;
    const float fac = __expf(-f) / L;
    const unsigned short* a0 = &pacc[r0 * 64 + q4 * 16];
    const unsigned short* a1 = &pacc[r1 * 64 + q4 * 16];
    unsigned short* dst = &abuf[(size_t)row * DIM_ + h * 64 + q4 * 16];
    #pragma unroll
    for (int k = 0; k < 4; k++) {
        const us4 x0 = *reinterpret_cast<const us4*>(&a0[k * 4]);
        const us4 x1 = *reinterpret_cast<const us4*>(&a1[k * 4]);
        us4 r;
        #pragma unroll
        for (int j = 0; j < 4; j++)
            r[j] = f2bf((bf2f(x0[j]) * w0 + bf2f(x1[j]) * w1) * fac);
        *reinterpret_cast<us4*>(&dst[k * 4]) = r;
    }
}

// out[row][col] = po0 + po1 + bias, fp32.
__global__ void o_combine(const unsigned short* __restrict__ po,
                          const float* __restrict__ ob,
                          float* __restrict__ out) {
    const int idx = blockIdx.x * 256 + threadIdx.x;      // 2048*512
    const int row = idx >> 9;
    const int c4 = (idx & 511) << 2;
    float4 o;
    const size_t r = (size_t)row * 2048 + c4;
    const us4 x0 = *reinterpret_cast<const us4*>(&po[r]);
    const us4 x1 = *reinterpret_cast<const us4*>(&po[4194304 + r]);
    o.x = bf2f(x0[0]) + bf2f(x1[0]) + ob[c4];
    o.y = bf2f(x0[1]) + bf2f(x1[1]) + ob[c4 + 1];
    o.z = bf2f(x0[2]) + bf2f(x1[2]) + ob[c4 + 2];
    o.w = bf2f(x0[3]) + bf2f(x1[3]) + ob[c4 + 3];
    *reinterpret_cast<float4*>(&out[r]) = o;
}

extern "C" void kernel_launch(void* const* d_in, const int* in_sizes, int n_in,
                              void* d_out, int out_size, void* d_ws, size_t ws_size,
                              hipStream_t stream) {
    const float* x     = (const float*)d_in[0];
    const float* rope  = (const float*)d_in[1];
    const float* wq_w  = (const float*)d_in[2];
    const float* wq_b  = (const float*)d_in[3];
    const float* wk_w  = (const float*)d_in[4];
    const float* wk_b  = (const float*)d_in[5];
    const float* wv_w  = (const float*)d_in[6];
    const float* wv_b  = (const float*)d_in[7];
    const float* wo_w  = (const float*)d_in[8];
    const float* wo_b  = (const float*)d_in[9];
    const float* sinks = (const float*)d_in[10];
    float* out = (float*)d_out;

    // ws layout (MB offsets, dead-region reuse):
    //  0: xb(8) -> qkbuf(10) -> po(16)        8: wqkv(12)   10: vtbuf(2)
    // 20: wob(8, live)                        28: pq(24) -> pacc(16)
    // 44: pml(2)   46: abuf(8)   54: bcat
    char* ws = (char*)d_ws;
    unsigned short* xb    = (unsigned short*)(ws);
    unsigned short* wqkv  = (unsigned short*)(ws + (8u  << 20));
    unsigned short* wob   = (unsigned short*)(ws + (20u << 20));
    unsigned short* pq    = (unsigned short*)(ws + (28u << 20));
    unsigned short* qkbuf = (unsigned short*)(ws);
    unsigned short* vtbuf = (unsigned short*)(ws + (10u << 20));
    unsigned short* pacc  = (unsigned short*)(ws + (28u << 20));
    float*          pml   = (float*)(ws + (44u << 20));
    unsigned short* abuf  = (unsigned short*)(ws + (46u << 20));
    unsigned short* po    = (unsigned short*)(ws);
    float*          bcat  = (float*)(ws + (54u << 20));

    cvt_all<<<14336, 256, 0, stream>>>(x, wq_w, wk_w, wv_w, wo_w, xb, wqkv, wob);
    build_bias<<<12, 256, 0, stream>>>(wq_b, wk_b, wv_b, bcat);

    gemm_part<<<dim3(24, 16, 2), 256, 0, stream>>>(xb, wqkv, pq, 2048, 3072);
    rope_combine<<<11264, 256, 0, stream>>>(pq, bcat, rope, qkbuf, vtbuf);
    attn_kernel<<<dim3(32, 64), 256, 0, stream>>>(qkbuf, vtbuf, pacc, pml);
    attn_combine<<<1024, 256, 0, stream>>>(pacc, pml, sinks, abuf);
    gemm_part<<<dim3(16, 16, 2), 256, 0, stream>>>(abuf, wob, po, 2048, 2048);
    o_combine<<<4096, 256, 0, stream>>>(po, wo_b, out);
}